// Round 3
// baseline (1281.780 us; speedup 1.0000x reference)
//
#include <hip/hip_runtime.h>
#include <hip/hip_bf16.h>

typedef __hip_bfloat16 bf16;
typedef __attribute__((ext_vector_type(8))) short bh8;   // 8 bf16 = 4 VGPRs
typedef __attribute__((ext_vector_type(4))) float f4;    // clang vector: ok for nontemporal

#define MFMA_BF16(a, b, c) __builtin_amdgcn_mfma_f32_16x16x32_bf16((a), (b), (c), 0, 0, 0)

union BH8U { bh8 v; bf16 e[8]; };

static const long ATTN_ELEMS = 134217728LL;  // 32*2048*2048

// ---------------------------------------------------------------------------
// dtype detector: if q is fp32, even 16-bit slots are fp32 low-halves ->
// exponent field uniform random -> many |x| >= 2^64. Real bf16 N(0,1) never.
// flag[0] = 1 -> fp32 inputs/outputs, 0 -> bf16.
// flag[1] initialized to 1 (mask==0 assumed true until k_maskzero refutes).
// ---------------------------------------------------------------------------
__global__ void k_detect(const unsigned short* __restrict__ q, int* __restrict__ flag) {
  __shared__ int cnt;
  if (threadIdx.x == 0) cnt = 0;
  __syncthreads();
  int c = 0;
  for (int i = threadIdx.x; i < 2048; i += 256) {
    const unsigned short u = q[2 * i];
    const int e = (u >> 7) & 0xFF;
    if (e >= 0xC0) ++c;
  }
  atomicAdd(&cnt, c);
  __syncthreads();
  if (threadIdx.x == 0) {
    flag[0] = (cnt > 64) ? 1 : 0;
    flag[1] = 1;  // mask-zero until proven otherwise
  }
}

// ---------------------------------------------------------------------------
// mask==0 check (treats +-0 as zero).  Any nonzero magnitude clears flag[1].
// ---------------------------------------------------------------------------
__global__ __launch_bounds__(256) void k_maskzero(const void* __restrict__ mask,
                                                  int* __restrict__ flag) {
  const int f = flag[0];
  const long nvec = f ? 2097152L : 1048576L;  // uint4 count: 32MB fp32 / 16MB bf16
  const unsigned int mbits = f ? 0x7fffffffu : 0x7fff7fffu;
  const uint4* W = (const uint4*)mask;
  unsigned int acc = 0;
  for (long i = (long)blockIdx.x * 256 + threadIdx.x; i < nvec;
       i += (long)gridDim.x * 256) {
    const uint4 w = W[i];
    acc |= (w.x | w.y | w.z | w.w);
  }
  if (acc & mbits) flag[1] = 0;  // benign race: only 0 is ever written
}

// ---------------------------------------------------------------------------
// convert raw (fp32 or bf16 per flag) -> canonical bf16.  8 elems/thread.
// ---------------------------------------------------------------------------
__device__ __forceinline__ void convert_body(const void* __restrict__ in,
                                             bf16* __restrict__ out, long n,
                                             int f) {
  const long idx = ((long)blockIdx.x * blockDim.x + threadIdx.x) * 8;
  if (idx >= n) return;
  if (f) {
    const float* F = (const float*)in + idx;
    const float4 a = *(const float4*)F;
    const float4 b = *(const float4*)(F + 4);
    BH8U u;
    u.e[0] = __float2bfloat16(a.x); u.e[1] = __float2bfloat16(a.y);
    u.e[2] = __float2bfloat16(a.z); u.e[3] = __float2bfloat16(a.w);
    u.e[4] = __float2bfloat16(b.x); u.e[5] = __float2bfloat16(b.y);
    u.e[6] = __float2bfloat16(b.z); u.e[7] = __float2bfloat16(b.w);
    *(bh8*)(out + idx) = u.v;
  } else {
    *(bh8*)(out + idx) = *(const bh8*)((const bf16*)in + idx);
  }
}

__global__ __launch_bounds__(256) void k_convert(const void* __restrict__ in,
                                                 bf16* __restrict__ out, long n,
                                                 const int* __restrict__ flagp) {
  convert_body(in, out, n, *flagp);
}

// batched q/k/v convert: grid.z selects the tensor
__global__ __launch_bounds__(256) void k_convert3(
    const void* __restrict__ i0, const void* __restrict__ i1,
    const void* __restrict__ i2, bf16* __restrict__ o0, bf16* __restrict__ o1,
    bf16* __restrict__ o2, const int* __restrict__ flagp) {
  const int z = blockIdx.z;
  const void* in = (z == 0) ? i0 : (z == 1) ? i1 : i2;
  bf16* out = (z == 0) ? o0 : (z == 1) ? o1 : o2;
  convert_body(in, out, 4194304L, *flagp);
}

// ---------------------------------------------------------------------------
// batched transpose of 4 raw [1024,1024] weights -> bf16 out[C][R]
// ---------------------------------------------------------------------------
__global__ __launch_bounds__(256) void k_transpose4(
    const void* __restrict__ i0, const void* __restrict__ i1,
    const void* __restrict__ i2, const void* __restrict__ i3,
    bf16* __restrict__ o0, bf16* __restrict__ o1, bf16* __restrict__ o2,
    bf16* __restrict__ o3, const int* __restrict__ flagp) {
  __shared__ bf16 tile[64][65];
  const int z = blockIdx.z;
  const void* in = (z == 0) ? i0 : (z == 1) ? i1 : (z == 2) ? i2 : i3;
  bf16* out = (z == 0) ? o0 : (z == 1) ? o1 : (z == 2) ? o2 : o3;
  const int R = 1024, C = 1024;
  const int f = *flagp;
  const int c0 = blockIdx.x * 64, r0 = blockIdx.y * 64;
  for (int i = threadIdx.x; i < 4096; i += 256) {
    const int r = i >> 6, c = i & 63;
    const long idx = (long)(r0 + r) * C + c0 + c;
    tile[r][c] = f ? __float2bfloat16(((const float*)in)[idx])
                   : ((const bf16*)in)[idx];
  }
  __syncthreads();
  for (int i = threadIdx.x; i < 4096; i += 256) {
    const int c = i >> 6, r = i & 63;
    out[(long)(c0 + c) * R + r0 + r] = tile[r][c];
  }
}

// ---------------------------------------------------------------------------
// V' [B*S, H*64] -> VT [B][H][64][2048]  (bf16 internal)
// ---------------------------------------------------------------------------
__global__ __launch_bounds__(256) void k_transpose_v(const bf16* __restrict__ Vp,
                                                     bf16* __restrict__ VT) {
  __shared__ bf16 tile[64][65];
  const int s0 = blockIdx.x * 64;
  const int h = blockIdx.y, b = blockIdx.z;
  for (int i = threadIdx.x; i < 4096; i += 256) {
    const int s = i >> 6, d = i & 63;
    tile[s][d] = Vp[(long)(b * 2048 + s0 + s) * 1024 + h * 64 + d];
  }
  __syncthreads();
  for (int i = threadIdx.x; i < 4096; i += 256) {
    const int d = i >> 6, s = i & 63;
    VT[((long)((b * 16 + h) * 64 + d)) * 2048 + s0 + s] = tile[s][d];
  }
}

// ---------------------------------------------------------------------------
// C = A[M,K] @ BT[N,K]^T * scale (+bias).  bf16 in, fp32 acc.
// If Cext != nullptr: external store to d_out (+ATTN_ELEMS) per *flagp dtype.
// ---------------------------------------------------------------------------
__device__ __forceinline__ void gemm_body(
    const bf16* __restrict__ A, const bf16* __restrict__ BT,
    bf16* __restrict__ C, char* __restrict__ Cext,
    const bf16* __restrict__ bias, const int* __restrict__ flagp,
    int M, int N, int K, float scale, bf16* As, bf16* Bs) {
  const int LD = 40;
  const int m0 = blockIdx.y * 128, n0 = blockIdx.x * 128;
  const int t = threadIdx.x;
  const int wave = t >> 6, lane = t & 63;
  const int wm = (wave >> 1) * 64, wn = (wave & 1) * 64;
  const int lr = lane & 15, lk = lane >> 4;

  const f4 fz = {0.f, 0.f, 0.f, 0.f};
  f4 acc[4][4];
#pragma unroll
  for (int i = 0; i < 4; ++i)
#pragma unroll
    for (int j = 0; j < 4; ++j) acc[i][j] = fz;

  const int srow = t >> 1;
  const int sch = (t & 1) * 16;
  const bf16* Ag = A + (long)(m0 + srow) * K + sch;
  const bf16* Bg = BT + (long)(n0 + srow) * K + sch;
  bf16* Asw = &As[srow * LD + sch];
  bf16* Bsw = &Bs[srow * LD + sch];

  for (int kb = 0; kb < K; kb += 32) {
    const bh8 a0 = *(const bh8*)(Ag + kb);
    const bh8 a1 = *(const bh8*)(Ag + kb + 8);
    const bh8 b0 = *(const bh8*)(Bg + kb);
    const bh8 b1 = *(const bh8*)(Bg + kb + 8);
    __syncthreads();
    *(bh8*)Asw = a0;
    *(bh8*)(Asw + 8) = a1;
    *(bh8*)Bsw = b0;
    *(bh8*)(Bsw + 8) = b1;
    __syncthreads();
    bh8 af[4], bfr[4];
#pragma unroll
    for (int i = 0; i < 4; ++i)
      af[i] = *(const bh8*)&As[(wm + i * 16 + lr) * LD + lk * 8];
#pragma unroll
    for (int j = 0; j < 4; ++j)
      bfr[j] = *(const bh8*)&Bs[(wn + j * 16 + lr) * LD + lk * 8];
#pragma unroll
    for (int i = 0; i < 4; ++i)
#pragma unroll
      for (int j = 0; j < 4; ++j) acc[i][j] = MFMA_BF16(af[i], bfr[j], acc[i][j]);
  }

  // C/D layout: col = lane&15, row = (lane>>4)*4 + r   [m89/m91]
  const int ext = (Cext != nullptr);
  const int f = ext ? *flagp : 0;
#pragma unroll
  for (int j = 0; j < 4; ++j) {
    const int n = n0 + wn + j * 16 + lr;
    const float bv = bias ? __bfloat162float(bias[n]) : 0.f;
#pragma unroll
    for (int i = 0; i < 4; ++i) {
      const int mr = m0 + wm + i * 16 + lk * 4;
#pragma unroll
      for (int r = 0; r < 4; ++r) {
        const float val = acc[i][j][r] * scale + bv;
        const long off = (long)(mr + r) * N + n;
        if (!ext) {
          C[off] = __float2bfloat16(val);
        } else if (f) {
          ((float*)Cext + ATTN_ELEMS)[off] = val;
        } else {
          ((bf16*)Cext + ATTN_ELEMS)[off] = __float2bfloat16(val);
        }
      }
    }
  }
}

__global__ __launch_bounds__(256) void k_gemm_bt(
    const bf16* __restrict__ A, const bf16* __restrict__ BT,
    bf16* __restrict__ C, char* __restrict__ Cext,
    const bf16* __restrict__ bias, const int* __restrict__ flagp,
    int M, int N, int K, float scale) {
  __shared__ bf16 As[128 * 40];
  __shared__ bf16 Bs[128 * 40];
  gemm_body(A, BT, C, Cext, bias, flagp, M, N, K, scale, As, Bs);
}

// batched q/k/v projections: grid.z selects — 3 blocks/CU overlap hides
// barrier/load stalls that a 256-block solo launch (1 block/CU) exposes.
__global__ __launch_bounds__(256) void k_gemm3(
    const bf16* __restrict__ A0, const bf16* __restrict__ A1,
    const bf16* __restrict__ A2, const bf16* __restrict__ B0,
    const bf16* __restrict__ B1, const bf16* __restrict__ B2,
    bf16* __restrict__ C0, bf16* __restrict__ C1, bf16* __restrict__ C2,
    float s0) {
  __shared__ bf16 As[128 * 40];
  __shared__ bf16 Bs[128 * 40];
  const int z = blockIdx.z;
  const bf16* A = (z == 0) ? A0 : (z == 1) ? A1 : A2;
  const bf16* BT = (z == 0) ? B0 : (z == 1) ? B1 : B2;
  bf16* C = (z == 0) ? C0 : (z == 1) ? C1 : C2;
  gemm_body(A, BT, C, nullptr, nullptr, nullptr, 4096, 1024, 1024,
            (z == 0) ? s0 : 1.0f, As, Bs);
}

// ---------------------------------------------------------------------------
// Fused attention, two-pass online softmax.  Qp pre-scaled 1/8.
// MZ=1: mask known all-zero -> skip all mask staging/convert/add.
// ---------------------------------------------------------------------------
template <int MZ>
__device__ __forceinline__ void attn_body(
    const bf16* __restrict__ Qp, const bf16* __restrict__ Kp,
    const bf16* __restrict__ VT, const void* __restrict__ mask,
    char* __restrict__ outbase, bf16* __restrict__ AV, const int f,
    bf16* Ks, bf16* Vs, bf16* Ps) {
  const int S = 2048, HD = 1024;
  const int q0 = blockIdx.x * 64;
  const int h = blockIdx.y, b = blockIdx.z;
  const int t = threadIdx.x;
  const int wave = t >> 6, lane = t & 63;
  const int lr = lane & 15, lk = lane >> 4;

  const bf16* qbase = Qp + (long)(b * S + q0 + wave * 16 + lr) * HD + h * 64 + lk * 8;
  const bh8 qf0 = *(const bh8*)qbase;
  const bh8 qf1 = *(const bh8*)(qbase + 32);

  const int srow = t >> 2;       // 0..63
  const int sch = (t & 3) * 16;  // 0,16,32,48
  const bf16* Kg = Kp + (long)b * S * HD + h * 64;
  const bf16* Vg = VT + ((long)((b * 16 + h) * 64 + srow)) * S + sch;
  const long moff = (long)b * S * S + (long)(q0 + srow) * S + sch;
  const float* MgF = (const float*)mask + moff;
  const bf16* MgB = (const bf16*)mask + moff;

  float mrun[4], lrun[4];
#pragma unroll
  for (int r = 0; r < 4; ++r) { mrun[r] = -1e30f; lrun[r] = 0.f; }

  // ---------------- pass 1: softmax stats ----------------
  for (int kt = 0; kt < S / 64; ++kt) {
    __syncthreads();
    {
      const bf16* src = Kg + (long)(kt * 64 + srow) * HD + sch;
      const bh8 x0 = *(const bh8*)src;
      const bh8 x1 = *(const bh8*)(src + 8);
      *(bh8*)&Ks[srow * 72 + sch] = x0;
      *(bh8*)&Ks[srow * 72 + sch + 8] = x1;
      if (!MZ) {
        if (f) {
          const float* M = MgF + kt * 64;
          const float4 m0 = ((const float4*)M)[0], m1 = ((const float4*)M)[1];
          const float4 m2 = ((const float4*)M)[2], m3 = ((const float4*)M)[3];
          BH8U u0, u1;
          u0.e[0] = __float2bfloat16(m0.x); u0.e[1] = __float2bfloat16(m0.y);
          u0.e[2] = __float2bfloat16(m0.z); u0.e[3] = __float2bfloat16(m0.w);
          u0.e[4] = __float2bfloat16(m1.x); u0.e[5] = __float2bfloat16(m1.y);
          u0.e[6] = __float2bfloat16(m1.z); u0.e[7] = __float2bfloat16(m1.w);
          u1.e[0] = __float2bfloat16(m2.x); u1.e[1] = __float2bfloat16(m2.y);
          u1.e[2] = __float2bfloat16(m2.z); u1.e[3] = __float2bfloat16(m2.w);
          u1.e[4] = __float2bfloat16(m3.x); u1.e[5] = __float2bfloat16(m3.y);
          u1.e[6] = __float2bfloat16(m3.z); u1.e[7] = __float2bfloat16(m3.w);
          *(bh8*)&Ps[srow * 72 + sch] = u0.v;
          *(bh8*)&Ps[srow * 72 + sch + 8] = u1.v;
        } else {
          *(bh8*)&Ps[srow * 72 + sch] = *(const bh8*)(MgB + kt * 64);
          *(bh8*)&Ps[srow * 72 + sch + 8] = *(const bh8*)(MgB + kt * 64 + 8);
        }
      }
    }
    __syncthreads();
    float s[4][4];
#pragma unroll
    for (int nf = 0; nf < 4; ++nf) {
      const bh8 kf0 = *(const bh8*)&Ks[(nf * 16 + lr) * 72 + lk * 8];
      const bh8 kf1 = *(const bh8*)&Ks[(nf * 16 + lr) * 72 + 32 + lk * 8];
      f4 a = {0.f, 0.f, 0.f, 0.f};
      a = MFMA_BF16(qf0, kf0, a);
      a = MFMA_BF16(qf1, kf1, a);
#pragma unroll
      for (int r = 0; r < 4; ++r) {
        const int trow = wave * 16 + lk * 4 + r;
        float sv = a[r];
        if (!MZ) sv += __bfloat162float(Ps[trow * 72 + nf * 16 + lr]);
        s[nf][r] = sv;
      }
    }
#pragma unroll
    for (int r = 0; r < 4; ++r) {
      float tm = fmaxf(fmaxf(s[0][r], s[1][r]), fmaxf(s[2][r], s[3][r]));
#pragma unroll
      for (int d = 1; d < 16; d <<= 1) tm = fmaxf(tm, __shfl_xor(tm, d, 64));
      const float mnew = fmaxf(mrun[r], tm);
      float ps = __expf(s[0][r] - mnew) + __expf(s[1][r] - mnew) +
                 __expf(s[2][r] - mnew) + __expf(s[3][r] - mnew);
#pragma unroll
      for (int d = 1; d < 16; d <<= 1) ps += __shfl_xor(ps, d, 64);
      lrun[r] = lrun[r] * __expf(mrun[r] - mnew) + ps;
      mrun[r] = mnew;
    }
  }

  float rl[4];
#pragma unroll
  for (int r = 0; r < 4; ++r) rl[r] = 1.f / lrun[r];

  const f4 fz = {0.f, 0.f, 0.f, 0.f};
  f4 oacc[4];
#pragma unroll
  for (int nf = 0; nf < 4; ++nf) oacc[nf] = fz;

  const long aoff = (long)(h * 2 + b) * S * S + (long)(q0 + srow) * S + sch;
  float* attnF = (float*)outbase + aoff;
  bf16* attnB = (bf16*)outbase + aoff;

  // ---------------- pass 2: attn write + P@V ----------------
  for (int kt = 0; kt < S / 64; ++kt) {
    __syncthreads();
    {
      const bf16* src = Kg + (long)(kt * 64 + srow) * HD + sch;
      const bh8 x0 = *(const bh8*)src;
      const bh8 x1 = *(const bh8*)(src + 8);
      const bh8 y0 = *(const bh8*)(Vg + kt * 64);
      const bh8 y1 = *(const bh8*)(Vg + kt * 64 + 8);
      *(bh8*)&Ks[srow * 72 + sch] = x0;
      *(bh8*)&Ks[srow * 72 + sch + 8] = x1;
      *(bh8*)&Vs[srow * 72 + sch] = y0;
      *(bh8*)&Vs[srow * 72 + sch + 8] = y1;
      if (!MZ) {
        if (f) {
          const float* M = MgF + kt * 64;
          const float4 m0 = ((const float4*)M)[0], m1 = ((const float4*)M)[1];
          const float4 m2 = ((const float4*)M)[2], m3 = ((const float4*)M)[3];
          BH8U u0, u1;
          u0.e[0] = __float2bfloat16(m0.x); u0.e[1] = __float2bfloat16(m0.y);
          u0.e[2] = __float2bfloat16(m0.z); u0.e[3] = __float2bfloat16(m0.w);
          u0.e[4] = __float2bfloat16(m1.x); u0.e[5] = __float2bfloat16(m1.y);
          u0.e[6] = __float2bfloat16(m1.z); u0.e[7] = __float2bfloat16(m1.w);
          u1.e[0] = __float2bfloat16(m2.x); u1.e[1] = __float2bfloat16(m2.y);
          u1.e[2] = __float2bfloat16(m2.z); u1.e[3] = __float2bfloat16(m2.w);
          u1.e[4] = __float2bfloat16(m3.x); u1.e[5] = __float2bfloat16(m3.y);
          u1.e[6] = __float2bfloat16(m3.z); u1.e[7] = __float2bfloat16(m3.w);
          *(bh8*)&Ps[srow * 72 + sch] = u0.v;
          *(bh8*)&Ps[srow * 72 + sch + 8] = u1.v;
        } else {
          *(bh8*)&Ps[srow * 72 + sch] = *(const bh8*)(MgB + kt * 64);
          *(bh8*)&Ps[srow * 72 + sch + 8] = *(const bh8*)(MgB + kt * 64 + 8);
        }
      }
    }
    __syncthreads();
#pragma unroll
    for (int nf = 0; nf < 4; ++nf) {
      const bh8 kf0 = *(const bh8*)&Ks[(nf * 16 + lr) * 72 + lk * 8];
      const bh8 kf1 = *(const bh8*)&Ks[(nf * 16 + lr) * 72 + 32 + lk * 8];
      f4 a = {0.f, 0.f, 0.f, 0.f};
      a = MFMA_BF16(qf0, kf0, a);
      a = MFMA_BF16(qf1, kf1, a);
#pragma unroll
      for (int r = 0; r < 4; ++r) {
        const int trow = wave * 16 + lk * 4 + r;
        float sv = a[r];
        if (!MZ) sv += __bfloat162float(Ps[trow * 72 + nf * 16 + lr]);
        const float p = __expf(sv - mrun[r]) * rl[r];
        Ps[trow * 72 + nf * 16 + lr] = __float2bfloat16(p);  // same-lane slot
      }
    }
    __syncthreads();
    {  // coalesced attention store from LDS (nontemporal: never re-read)
      BH8U p0, p1;
      p0.v = *(const bh8*)&Ps[srow * 72 + sch];
      p1.v = *(const bh8*)&Ps[srow * 72 + sch + 8];
      if (f) {
        float* dst = attnF + kt * 64;
        const f4 o0 = {__bfloat162float(p0.e[0]), __bfloat162float(p0.e[1]),
                       __bfloat162float(p0.e[2]), __bfloat162float(p0.e[3])};
        const f4 o1 = {__bfloat162float(p0.e[4]), __bfloat162float(p0.e[5]),
                       __bfloat162float(p0.e[6]), __bfloat162float(p0.e[7])};
        const f4 o2 = {__bfloat162float(p1.e[0]), __bfloat162float(p1.e[1]),
                       __bfloat162float(p1.e[2]), __bfloat162float(p1.e[3])};
        const f4 o3 = {__bfloat162float(p1.e[4]), __bfloat162float(p1.e[5]),
                       __bfloat162float(p1.e[6]), __bfloat162float(p1.e[7])};
        __builtin_nontemporal_store(o0, (f4*)dst + 0);
        __builtin_nontemporal_store(o1, (f4*)dst + 1);
        __builtin_nontemporal_store(o2, (f4*)dst + 2);
        __builtin_nontemporal_store(o3, (f4*)dst + 3);
      } else {
        bf16* dst = attnB + kt * 64;
        __builtin_nontemporal_store(p0.v, (bh8*)dst);
        __builtin_nontemporal_store(p1.v, (bh8*)(dst + 8));
      }
    }
    const bh8 pa0 = *(const bh8*)&Ps[(wave * 16 + lr) * 72 + lk * 8];
    const bh8 pa1 = *(const bh8*)&Ps[(wave * 16 + lr) * 72 + 32 + lk * 8];
#pragma unroll
    for (int nf = 0; nf < 4; ++nf) {
      const bh8 vb0 = *(const bh8*)&Vs[(nf * 16 + lr) * 72 + lk * 8];
      const bh8 vb1 = *(const bh8*)&Vs[(nf * 16 + lr) * 72 + 32 + lk * 8];
      oacc[nf] = MFMA_BF16(pa0, vb0, oacc[nf]);
      oacc[nf] = MFMA_BF16(pa1, vb1, oacc[nf]);
    }
  }

#pragma unroll
  for (int nf = 0; nf < 4; ++nf) {
#pragma unroll
    for (int r = 0; r < 4; ++r) {
      const int qrow = q0 + wave * 16 + lk * 4 + r;
      AV[(long)(b * S + qrow) * HD + h * 64 + nf * 16 + lr] =
          __float2bfloat16(oacc[nf][r]);
    }
  }
}

__global__ __launch_bounds__(256) void k_attn(
    const bf16* __restrict__ Qp, const bf16* __restrict__ Kp,
    const bf16* __restrict__ VT, const void* __restrict__ mask,
    char* __restrict__ outbase, bf16* __restrict__ AV,
    const int* __restrict__ flagp) {
  __shared__ bf16 Ks[64 * 72];
  __shared__ bf16 Vs[64 * 72];
  __shared__ bf16 Ps[64 * 72];
  const int f = flagp[0];
  if (flagp[1])
    attn_body<1>(Qp, Kp, VT, mask, outbase, AV, f, Ks, Vs, Ps);
  else
    attn_body<0>(Qp, Kp, VT, mask, outbase, AV, f, Ks, Vs, Ps);
}

// ---------------------------------------------------------------------------
extern "C" void kernel_launch(void* const* d_in, const int* in_sizes, int n_in,
                              void* d_out, int out_size, void* d_ws, size_t ws_size,
                              hipStream_t stream) {
  const void* q    = d_in[0];
  const void* k    = d_in[1];
  const void* v    = d_in[2];
  const void* mask = d_in[3];
  const void* Wq   = d_in[4];
  const void* Wk   = d_in[5];
  const void* Wv   = d_in[6];
  const void* Wo   = d_in[7];
  const void* bo   = d_in[8];

  char* ws = (char*)d_ws;
  const size_t MB = 1024 * 1024;
  bf16* WqT = (bf16*)(ws + 0 * MB);
  bf16* WkT = (bf16*)(ws + 2 * MB);
  bf16* WvT = (bf16*)(ws + 4 * MB);
  bf16* WoT = (bf16*)(ws + 6 * MB);
  bf16* boC = (bf16*)(ws + 8 * MB);
  int* flag = (int*)(ws + 8 * MB + 8192);
  bf16* Qp  = (bf16*)(ws + 9 * MB);
  bf16* Kp  = (bf16*)(ws + 17 * MB);
  bf16* VTr = (bf16*)(ws + 25 * MB);
  bf16* AV  = (bf16*)(ws + 33 * MB);   // ends at 41 MB

  // canonical q/k/v and V' live in d_out's attention region (dead before
  // k_attn writes attention; stream-ordered)
  char* ob = (char*)d_out;
  bf16* qc = (bf16*)(ob + 0 * MB);
  bf16* kc = (bf16*)(ob + 8 * MB);
  bf16* vc = (bf16*)(ob + 16 * MB);
  bf16* Vp = (bf16*)(ob + 24 * MB);    // ends at 32 MB << 256 MB

  k_detect<<<1, 256, 0, stream>>>((const unsigned short*)q, flag);
  k_maskzero<<<2048, 256, 0, stream>>>(mask, flag);

  k_convert3<<<dim3(2048, 1, 3), 256, 0, stream>>>(q, k, v, qc, kc, vc, flag);
  k_convert<<<1, 256, 0, stream>>>(bo, boC, 1024, flag);

  k_transpose4<<<dim3(16, 16, 4), 256, 0, stream>>>(Wq, Wk, Wv, Wo, WqT, WkT,
                                                    WvT, WoT, flag);

  k_gemm3<<<dim3(8, 32, 3), 256, 0, stream>>>(qc, kc, vc, WqT, WkT, WvT, Qp, Kp,
                                              Vp, 0.125f);

  k_transpose_v<<<dim3(32, 16, 2), 256, 0, stream>>>(Vp, VTr);

  k_attn<<<dim3(32, 16, 2), 256, 0, stream>>>(Qp, Kp, VTr, mask, ob, AV, flag);

  const dim3 ggrid(8, 32);
  k_gemm_bt<<<ggrid, 256, 0, stream>>>(AV, WoT, nullptr, ob, boC, flag,
                                       4096, 1024, 1024, 1.0f);
}

// Round 4
// 885.082 us; speedup vs baseline: 1.4482x; 1.4482x over previous
//
#include <hip/hip_runtime.h>
#include <hip/hip_bf16.h>

typedef __hip_bfloat16 bf16;
typedef __attribute__((ext_vector_type(8))) short bh8;   // 8 bf16 = 4 VGPRs
typedef __attribute__((ext_vector_type(4))) float f4;

#define MFMA_BF16(a, b, c) __builtin_amdgcn_mfma_f32_16x16x32_bf16((a), (b), (c), 0, 0, 0)

union BH8U { bh8 v; bf16 e[8]; };

static const long ATTN_ELEMS = 134217728LL;  // 32*2048*2048

// ---------------------------------------------------------------------------
// dtype detector: if q is fp32, even 16-bit slots are fp32 low-halves ->
// exponent field uniform random -> many |x| >= 2^64. Real bf16 N(0,1) never.
// flag[0] = 1 -> fp32 inputs/outputs, 0 -> bf16.
// flag[1] initialized to 1 (mask==0 assumed true until k_maskzero refutes).
// ---------------------------------------------------------------------------
__global__ void k_detect(const unsigned short* __restrict__ q, int* __restrict__ flag) {
  __shared__ int cnt;
  if (threadIdx.x == 0) cnt = 0;
  __syncthreads();
  int c = 0;
  for (int i = threadIdx.x; i < 2048; i += 256) {
    const unsigned short u = q[2 * i];
    const int e = (u >> 7) & 0xFF;
    if (e >= 0xC0) ++c;
  }
  atomicAdd(&cnt, c);
  __syncthreads();
  if (threadIdx.x == 0) {
    flag[0] = (cnt > 64) ? 1 : 0;
    flag[1] = 1;  // mask-zero until proven otherwise
  }
}

// ---------------------------------------------------------------------------
// mask==0 check (treats +-0 as zero).  Any nonzero magnitude clears flag[1].
// ---------------------------------------------------------------------------
__global__ __launch_bounds__(256) void k_maskzero(const void* __restrict__ mask,
                                                  int* __restrict__ flag) {
  const int f = flag[0];
  const long nvec = f ? 2097152L : 1048576L;  // uint4 count: 32MB fp32 / 16MB bf16
  const unsigned int mbits = f ? 0x7fffffffu : 0x7fff7fffu;
  const uint4* W = (const uint4*)mask;
  unsigned int acc = 0;
  for (long i = (long)blockIdx.x * 256 + threadIdx.x; i < nvec;
       i += (long)gridDim.x * 256) {
    const uint4 w = W[i];
    acc |= (w.x | w.y | w.z | w.w);
  }
  if (acc & mbits) flag[1] = 0;  // benign race: only 0 is ever written
}

// ---------------------------------------------------------------------------
// convert raw (fp32 or bf16 per flag) -> canonical bf16.  8 elems/thread.
// ---------------------------------------------------------------------------
__device__ __forceinline__ void convert_body(const void* __restrict__ in,
                                             bf16* __restrict__ out, long n,
                                             int f) {
  const long idx = ((long)blockIdx.x * blockDim.x + threadIdx.x) * 8;
  if (idx >= n) return;
  if (f) {
    const float* F = (const float*)in + idx;
    const float4 a = *(const float4*)F;
    const float4 b = *(const float4*)(F + 4);
    BH8U u;
    u.e[0] = __float2bfloat16(a.x); u.e[1] = __float2bfloat16(a.y);
    u.e[2] = __float2bfloat16(a.z); u.e[3] = __float2bfloat16(a.w);
    u.e[4] = __float2bfloat16(b.x); u.e[5] = __float2bfloat16(b.y);
    u.e[6] = __float2bfloat16(b.z); u.e[7] = __float2bfloat16(b.w);
    *(bh8*)(out + idx) = u.v;
  } else {
    *(bh8*)(out + idx) = *(const bh8*)((const bf16*)in + idx);
  }
}

__global__ __launch_bounds__(256) void k_convert(const void* __restrict__ in,
                                                 bf16* __restrict__ out, long n,
                                                 const int* __restrict__ flagp) {
  convert_body(in, out, n, *flagp);
}

// batched q/k/v convert: grid.z selects the tensor
__global__ __launch_bounds__(256) void k_convert3(
    const void* __restrict__ i0, const void* __restrict__ i1,
    const void* __restrict__ i2, bf16* __restrict__ o0, bf16* __restrict__ o1,
    bf16* __restrict__ o2, const int* __restrict__ flagp) {
  const int z = blockIdx.z;
  const void* in = (z == 0) ? i0 : (z == 1) ? i1 : i2;
  bf16* out = (z == 0) ? o0 : (z == 1) ? o1 : o2;
  convert_body(in, out, 4194304L, *flagp);
}

// ---------------------------------------------------------------------------
// batched transpose of 4 raw [1024,1024] weights -> bf16 out[C][R]
// ---------------------------------------------------------------------------
__global__ __launch_bounds__(256) void k_transpose4(
    const void* __restrict__ i0, const void* __restrict__ i1,
    const void* __restrict__ i2, const void* __restrict__ i3,
    bf16* __restrict__ o0, bf16* __restrict__ o1, bf16* __restrict__ o2,
    bf16* __restrict__ o3, const int* __restrict__ flagp) {
  __shared__ bf16 tile[64][65];
  const int z = blockIdx.z;
  const void* in = (z == 0) ? i0 : (z == 1) ? i1 : (z == 2) ? i2 : i3;
  bf16* out = (z == 0) ? o0 : (z == 1) ? o1 : (z == 2) ? o2 : o3;
  const int R = 1024, C = 1024;
  const int f = *flagp;
  const int c0 = blockIdx.x * 64, r0 = blockIdx.y * 64;
  for (int i = threadIdx.x; i < 4096; i += 256) {
    const int r = i >> 6, c = i & 63;
    const long idx = (long)(r0 + r) * C + c0 + c;
    tile[r][c] = f ? __float2bfloat16(((const float*)in)[idx])
                   : ((const bf16*)in)[idx];
  }
  __syncthreads();
  for (int i = threadIdx.x; i < 4096; i += 256) {
    const int c = i >> 6, r = i & 63;
    out[(long)(c0 + c) * R + r0 + r] = tile[r][c];
  }
}

// ---------------------------------------------------------------------------
// V' [B*S, H*64] -> VT [B][H][64][2048]  (bf16 internal)
// ---------------------------------------------------------------------------
__global__ __launch_bounds__(256) void k_transpose_v(const bf16* __restrict__ Vp,
                                                     bf16* __restrict__ VT) {
  __shared__ bf16 tile[64][65];
  const int s0 = blockIdx.x * 64;
  const int h = blockIdx.y, b = blockIdx.z;
  for (int i = threadIdx.x; i < 4096; i += 256) {
    const int s = i >> 6, d = i & 63;
    tile[s][d] = Vp[(long)(b * 2048 + s0 + s) * 1024 + h * 64 + d];
  }
  __syncthreads();
  for (int i = threadIdx.x; i < 4096; i += 256) {
    const int d = i >> 6, s = i & 63;
    VT[((long)((b * 16 + h) * 64 + d)) * 2048 + s0 + s] = tile[s][d];
  }
}

// ---------------------------------------------------------------------------
// C = A[M,K] @ BT[N,K]^T * scale (+bias).  bf16 in, fp32 acc.
// If Cext != nullptr: external store to d_out (+ATTN_ELEMS) per *flagp dtype.
// ---------------------------------------------------------------------------
__device__ __forceinline__ void gemm_body(
    const bf16* __restrict__ A, const bf16* __restrict__ BT,
    bf16* __restrict__ C, char* __restrict__ Cext,
    const bf16* __restrict__ bias, const int* __restrict__ flagp,
    int M, int N, int K, float scale, bf16* As, bf16* Bs) {
  const int LD = 40;
  const int m0 = blockIdx.y * 128, n0 = blockIdx.x * 128;
  const int t = threadIdx.x;
  const int wave = t >> 6, lane = t & 63;
  const int wm = (wave >> 1) * 64, wn = (wave & 1) * 64;
  const int lr = lane & 15, lk = lane >> 4;

  const f4 fz = {0.f, 0.f, 0.f, 0.f};
  f4 acc[4][4];
#pragma unroll
  for (int i = 0; i < 4; ++i)
#pragma unroll
    for (int j = 0; j < 4; ++j) acc[i][j] = fz;

  const int srow = t >> 1;
  const int sch = (t & 1) * 16;
  const bf16* Ag = A + (long)(m0 + srow) * K + sch;
  const bf16* Bg = BT + (long)(n0 + srow) * K + sch;
  bf16* Asw = &As[srow * LD + sch];
  bf16* Bsw = &Bs[srow * LD + sch];

  for (int kb = 0; kb < K; kb += 32) {
    const bh8 a0 = *(const bh8*)(Ag + kb);
    const bh8 a1 = *(const bh8*)(Ag + kb + 8);
    const bh8 b0 = *(const bh8*)(Bg + kb);
    const bh8 b1 = *(const bh8*)(Bg + kb + 8);
    __syncthreads();
    *(bh8*)Asw = a0;
    *(bh8*)(Asw + 8) = a1;
    *(bh8*)Bsw = b0;
    *(bh8*)(Bsw + 8) = b1;
    __syncthreads();
    bh8 af[4], bfr[4];
#pragma unroll
    for (int i = 0; i < 4; ++i)
      af[i] = *(const bh8*)&As[(wm + i * 16 + lr) * LD + lk * 8];
#pragma unroll
    for (int j = 0; j < 4; ++j)
      bfr[j] = *(const bh8*)&Bs[(wn + j * 16 + lr) * LD + lk * 8];
#pragma unroll
    for (int i = 0; i < 4; ++i)
#pragma unroll
      for (int j = 0; j < 4; ++j) acc[i][j] = MFMA_BF16(af[i], bfr[j], acc[i][j]);
  }

  // C/D layout: col = lane&15, row = (lane>>4)*4 + r   [m89/m91]
  const int ext = (Cext != nullptr);
  const int f = ext ? *flagp : 0;
#pragma unroll
  for (int j = 0; j < 4; ++j) {
    const int n = n0 + wn + j * 16 + lr;
    const float bv = bias ? __bfloat162float(bias[n]) : 0.f;
#pragma unroll
    for (int i = 0; i < 4; ++i) {
      const int mr = m0 + wm + i * 16 + lk * 4;
#pragma unroll
      for (int r = 0; r < 4; ++r) {
        const float val = acc[i][j][r] * scale + bv;
        const long off = (long)(mr + r) * N + n;
        if (!ext) {
          C[off] = __float2bfloat16(val);
        } else if (f) {
          ((float*)Cext + ATTN_ELEMS)[off] = val;
        } else {
          ((bf16*)Cext + ATTN_ELEMS)[off] = __float2bfloat16(val);
        }
      }
    }
  }
}

__global__ __launch_bounds__(256) void k_gemm_bt(
    const bf16* __restrict__ A, const bf16* __restrict__ BT,
    bf16* __restrict__ C, char* __restrict__ Cext,
    const bf16* __restrict__ bias, const int* __restrict__ flagp,
    int M, int N, int K, float scale) {
  __shared__ bf16 As[128 * 40];
  __shared__ bf16 Bs[128 * 40];
  gemm_body(A, BT, C, Cext, bias, flagp, M, N, K, scale, As, Bs);
}

// batched q/k/v projections: grid.z selects — 3 blocks/CU overlap hides
// barrier/load stalls that a 256-block solo launch (1 block/CU) exposes.
__global__ __launch_bounds__(256) void k_gemm3(
    const bf16* __restrict__ A0, const bf16* __restrict__ A1,
    const bf16* __restrict__ A2, const bf16* __restrict__ B0,
    const bf16* __restrict__ B1, const bf16* __restrict__ B2,
    bf16* __restrict__ C0, bf16* __restrict__ C1, bf16* __restrict__ C2,
    float s0) {
  __shared__ bf16 As[128 * 40];
  __shared__ bf16 Bs[128 * 40];
  const int z = blockIdx.z;
  const bf16* A = (z == 0) ? A0 : (z == 1) ? A1 : A2;
  const bf16* BT = (z == 0) ? B0 : (z == 1) ? B1 : B2;
  bf16* C = (z == 0) ? C0 : (z == 1) ? C1 : C2;
  gemm_body(A, BT, C, nullptr, nullptr, nullptr, 4096, 1024, 1024,
            (z == 0) ? s0 : 1.0f, As, Bs);
}

// ---------------------------------------------------------------------------
// Fused attention, two-pass online softmax.  Qp pre-scaled 1/8.
// MZ=1: mask known all-zero -> skip all mask staging/convert/add.
// Attention stores are PLAIN (L2 write-back) — nt stores regressed 2x (R3).
// ---------------------------------------------------------------------------
template <int MZ>
__device__ __forceinline__ void attn_body(
    const bf16* __restrict__ Qp, const bf16* __restrict__ Kp,
    const bf16* __restrict__ VT, const void* __restrict__ mask,
    char* __restrict__ outbase, bf16* __restrict__ AV, const int f,
    bf16* Ks, bf16* Vs, bf16* Ps) {
  const int S = 2048, HD = 1024;
  const int q0 = blockIdx.x * 64;
  const int h = blockIdx.y, b = blockIdx.z;
  const int t = threadIdx.x;
  const int wave = t >> 6, lane = t & 63;
  const int lr = lane & 15, lk = lane >> 4;

  const bf16* qbase = Qp + (long)(b * S + q0 + wave * 16 + lr) * HD + h * 64 + lk * 8;
  const bh8 qf0 = *(const bh8*)qbase;
  const bh8 qf1 = *(const bh8*)(qbase + 32);

  const int srow = t >> 2;       // 0..63
  const int sch = (t & 3) * 16;  // 0,16,32,48
  const bf16* Kg = Kp + (long)b * S * HD + h * 64;
  const bf16* Vg = VT + ((long)((b * 16 + h) * 64 + srow)) * S + sch;
  const long moff = (long)b * S * S + (long)(q0 + srow) * S + sch;
  const float* MgF = (const float*)mask + moff;
  const bf16* MgB = (const bf16*)mask + moff;

  float mrun[4], lrun[4];
#pragma unroll
  for (int r = 0; r < 4; ++r) { mrun[r] = -1e30f; lrun[r] = 0.f; }

  // ---------------- pass 1: softmax stats ----------------
  for (int kt = 0; kt < S / 64; ++kt) {
    __syncthreads();
    {
      const bf16* src = Kg + (long)(kt * 64 + srow) * HD + sch;
      const bh8 x0 = *(const bh8*)src;
      const bh8 x1 = *(const bh8*)(src + 8);
      *(bh8*)&Ks[srow * 72 + sch] = x0;
      *(bh8*)&Ks[srow * 72 + sch + 8] = x1;
      if (!MZ) {
        if (f) {
          const float* M = MgF + kt * 64;
          const float4 m0 = ((const float4*)M)[0], m1 = ((const float4*)M)[1];
          const float4 m2 = ((const float4*)M)[2], m3 = ((const float4*)M)[3];
          BH8U u0, u1;
          u0.e[0] = __float2bfloat16(m0.x); u0.e[1] = __float2bfloat16(m0.y);
          u0.e[2] = __float2bfloat16(m0.z); u0.e[3] = __float2bfloat16(m0.w);
          u0.e[4] = __float2bfloat16(m1.x); u0.e[5] = __float2bfloat16(m1.y);
          u0.e[6] = __float2bfloat16(m1.z); u0.e[7] = __float2bfloat16(m1.w);
          u1.e[0] = __float2bfloat16(m2.x); u1.e[1] = __float2bfloat16(m2.y);
          u1.e[2] = __float2bfloat16(m2.z); u1.e[3] = __float2bfloat16(m2.w);
          u1.e[4] = __float2bfloat16(m3.x); u1.e[5] = __float2bfloat16(m3.y);
          u1.e[6] = __float2bfloat16(m3.z); u1.e[7] = __float2bfloat16(m3.w);
          *(bh8*)&Ps[srow * 72 + sch] = u0.v;
          *(bh8*)&Ps[srow * 72 + sch + 8] = u1.v;
        } else {
          *(bh8*)&Ps[srow * 72 + sch] = *(const bh8*)(MgB + kt * 64);
          *(bh8*)&Ps[srow * 72 + sch + 8] = *(const bh8*)(MgB + kt * 64 + 8);
        }
      }
    }
    __syncthreads();
    float s[4][4];
#pragma unroll
    for (int nf = 0; nf < 4; ++nf) {
      const bh8 kf0 = *(const bh8*)&Ks[(nf * 16 + lr) * 72 + lk * 8];
      const bh8 kf1 = *(const bh8*)&Ks[(nf * 16 + lr) * 72 + 32 + lk * 8];
      f4 a = {0.f, 0.f, 0.f, 0.f};
      a = MFMA_BF16(qf0, kf0, a);
      a = MFMA_BF16(qf1, kf1, a);
#pragma unroll
      for (int r = 0; r < 4; ++r) {
        const int trow = wave * 16 + lk * 4 + r;
        float sv = a[r];
        if (!MZ) sv += __bfloat162float(Ps[trow * 72 + nf * 16 + lr]);
        s[nf][r] = sv;
      }
    }
#pragma unroll
    for (int r = 0; r < 4; ++r) {
      float tm = fmaxf(fmaxf(s[0][r], s[1][r]), fmaxf(s[2][r], s[3][r]));
#pragma unroll
      for (int d = 1; d < 16; d <<= 1) tm = fmaxf(tm, __shfl_xor(tm, d, 64));
      const float mnew = fmaxf(mrun[r], tm);
      float ps = __expf(s[0][r] - mnew) + __expf(s[1][r] - mnew) +
                 __expf(s[2][r] - mnew) + __expf(s[3][r] - mnew);
#pragma unroll
      for (int d = 1; d < 16; d <<= 1) ps += __shfl_xor(ps, d, 64);
      lrun[r] = lrun[r] * __expf(mrun[r] - mnew) + ps;
      mrun[r] = mnew;
    }
  }

  float rl[4];
#pragma unroll
  for (int r = 0; r < 4; ++r) rl[r] = 1.f / lrun[r];

  const f4 fz = {0.f, 0.f, 0.f, 0.f};
  f4 oacc[4];
#pragma unroll
  for (int nf = 0; nf < 4; ++nf) oacc[nf] = fz;

  const long aoff = (long)(h * 2 + b) * S * S + (long)(q0 + srow) * S + sch;
  float* attnF = (float*)outbase + aoff;
  bf16* attnB = (bf16*)outbase + aoff;

  // ---------------- pass 2: attn write + P@V ----------------
  for (int kt = 0; kt < S / 64; ++kt) {
    __syncthreads();
    {
      const bf16* src = Kg + (long)(kt * 64 + srow) * HD + sch;
      const bh8 x0 = *(const bh8*)src;
      const bh8 x1 = *(const bh8*)(src + 8);
      const bh8 y0 = *(const bh8*)(Vg + kt * 64);
      const bh8 y1 = *(const bh8*)(Vg + kt * 64 + 8);
      *(bh8*)&Ks[srow * 72 + sch] = x0;
      *(bh8*)&Ks[srow * 72 + sch + 8] = x1;
      *(bh8*)&Vs[srow * 72 + sch] = y0;
      *(bh8*)&Vs[srow * 72 + sch + 8] = y1;
      if (!MZ) {
        if (f) {
          const float* M = MgF + kt * 64;
          const float4 m0 = ((const float4*)M)[0], m1 = ((const float4*)M)[1];
          const float4 m2 = ((const float4*)M)[2], m3 = ((const float4*)M)[3];
          BH8U u0, u1;
          u0.e[0] = __float2bfloat16(m0.x); u0.e[1] = __float2bfloat16(m0.y);
          u0.e[2] = __float2bfloat16(m0.z); u0.e[3] = __float2bfloat16(m0.w);
          u0.e[4] = __float2bfloat16(m1.x); u0.e[5] = __float2bfloat16(m1.y);
          u0.e[6] = __float2bfloat16(m1.z); u0.e[7] = __float2bfloat16(m1.w);
          u1.e[0] = __float2bfloat16(m2.x); u1.e[1] = __float2bfloat16(m2.y);
          u1.e[2] = __float2bfloat16(m2.z); u1.e[3] = __float2bfloat16(m2.w);
          u1.e[4] = __float2bfloat16(m3.x); u1.e[5] = __float2bfloat16(m3.y);
          u1.e[6] = __float2bfloat16(m3.z); u1.e[7] = __float2bfloat16(m3.w);
          *(bh8*)&Ps[srow * 72 + sch] = u0.v;
          *(bh8*)&Ps[srow * 72 + sch + 8] = u1.v;
        } else {
          *(bh8*)&Ps[srow * 72 + sch] = *(const bh8*)(MgB + kt * 64);
          *(bh8*)&Ps[srow * 72 + sch + 8] = *(const bh8*)(MgB + kt * 64 + 8);
        }
      }
    }
    __syncthreads();
#pragma unroll
    for (int nf = 0; nf < 4; ++nf) {
      const bh8 kf0 = *(const bh8*)&Ks[(nf * 16 + lr) * 72 + lk * 8];
      const bh8 kf1 = *(const bh8*)&Ks[(nf * 16 + lr) * 72 + 32 + lk * 8];
      f4 a = {0.f, 0.f, 0.f, 0.f};
      a = MFMA_BF16(qf0, kf0, a);
      a = MFMA_BF16(qf1, kf1, a);
#pragma unroll
      for (int r = 0; r < 4; ++r) {
        const int trow = wave * 16 + lk * 4 + r;
        float sv = a[r];
        if (!MZ) sv += __bfloat162float(Ps[trow * 72 + nf * 16 + lr]);
        const float p = __expf(sv - mrun[r]) * rl[r];
        Ps[trow * 72 + nf * 16 + lr] = __float2bfloat16(p);  // same-lane slot
      }
    }
    __syncthreads();
    {  // coalesced attention store from LDS (plain stores; L2 write-back)
      BH8U p0, p1;
      p0.v = *(const bh8*)&Ps[srow * 72 + sch];
      p1.v = *(const bh8*)&Ps[srow * 72 + sch + 8];
      if (f) {
        float* dst = attnF + kt * 64;
        const float4 o0 = {__bfloat162float(p0.e[0]), __bfloat162float(p0.e[1]),
                           __bfloat162float(p0.e[2]), __bfloat162float(p0.e[3])};
        const float4 o1 = {__bfloat162float(p0.e[4]), __bfloat162float(p0.e[5]),
                           __bfloat162float(p0.e[6]), __bfloat162float(p0.e[7])};
        const float4 o2 = {__bfloat162float(p1.e[0]), __bfloat162float(p1.e[1]),
                           __bfloat162float(p1.e[2]), __bfloat162float(p1.e[3])};
        const float4 o3 = {__bfloat162float(p1.e[4]), __bfloat162float(p1.e[5]),
                           __bfloat162float(p1.e[6]), __bfloat162float(p1.e[7])};
        ((float4*)dst)[0] = o0;
        ((float4*)dst)[1] = o1;
        ((float4*)dst)[2] = o2;
        ((float4*)dst)[3] = o3;
      } else {
        bf16* dst = attnB + kt * 64;
        *(bh8*)dst = p0.v;
        *(bh8*)(dst + 8) = p1.v;
      }
    }
    const bh8 pa0 = *(const bh8*)&Ps[(wave * 16 + lr) * 72 + lk * 8];
    const bh8 pa1 = *(const bh8*)&Ps[(wave * 16 + lr) * 72 + 32 + lk * 8];
#pragma unroll
    for (int nf = 0; nf < 4; ++nf) {
      const bh8 vb0 = *(const bh8*)&Vs[(nf * 16 + lr) * 72 + lk * 8];
      const bh8 vb1 = *(const bh8*)&Vs[(nf * 16 + lr) * 72 + 32 + lk * 8];
      oacc[nf] = MFMA_BF16(pa0, vb0, oacc[nf]);
      oacc[nf] = MFMA_BF16(pa1, vb1, oacc[nf]);
    }
  }

#pragma unroll
  for (int nf = 0; nf < 4; ++nf) {
#pragma unroll
    for (int r = 0; r < 4; ++r) {
      const int qrow = q0 + wave * 16 + lk * 4 + r;
      AV[(long)(b * S + qrow) * HD + h * 64 + nf * 16 + lr] =
          __float2bfloat16(oacc[nf][r]);
    }
  }
}

__global__ __launch_bounds__(256) void k_attn(
    const bf16* __restrict__ Qp, const bf16* __restrict__ Kp,
    const bf16* __restrict__ VT, const void* __restrict__ mask,
    char* __restrict__ outbase, bf16* __restrict__ AV,
    const int* __restrict__ flagp) {
  __shared__ bf16 Ks[64 * 72];
  __shared__ bf16 Vs[64 * 72];
  __shared__ bf16 Ps[64 * 72];
  const int f = flagp[0];
  if (flagp[1])
    attn_body<1>(Qp, Kp, VT, mask, outbase, AV, f, Ks, Vs, Ps);
  else
    attn_body<0>(Qp, Kp, VT, mask, outbase, AV, f, Ks, Vs, Ps);
}

// ---------------------------------------------------------------------------
extern "C" void kernel_launch(void* const* d_in, const int* in_sizes, int n_in,
                              void* d_out, int out_size, void* d_ws, size_t ws_size,
                              hipStream_t stream) {
  const void* q    = d_in[0];
  const void* k    = d_in[1];
  const void* v    = d_in[2];
  const void* mask = d_in[3];
  const void* Wq   = d_in[4];
  const void* Wk   = d_in[5];
  const void* Wv   = d_in[6];
  const void* Wo   = d_in[7];
  const void* bo   = d_in[8];

  char* ws = (char*)d_ws;
  const size_t MB = 1024 * 1024;
  bf16* WqT = (bf16*)(ws + 0 * MB);
  bf16* WkT = (bf16*)(ws + 2 * MB);
  bf16* WvT = (bf16*)(ws + 4 * MB);
  bf16* WoT = (bf16*)(ws + 6 * MB);
  bf16* boC = (bf16*)(ws + 8 * MB);
  int* flag = (int*)(ws + 8 * MB + 8192);
  bf16* Qp  = (bf16*)(ws + 9 * MB);
  bf16* Kp  = (bf16*)(ws + 17 * MB);
  bf16* VTr = (bf16*)(ws + 25 * MB);
  bf16* AV  = (bf16*)(ws + 33 * MB);   // ends at 41 MB

  // canonical q/k/v and V' live in d_out's attention region (dead before
  // k_attn writes attention; stream-ordered)
  char* ob = (char*)d_out;
  bf16* qc = (bf16*)(ob + 0 * MB);
  bf16* kc = (bf16*)(ob + 8 * MB);
  bf16* vc = (bf16*)(ob + 16 * MB);
  bf16* Vp = (bf16*)(ob + 24 * MB);    // ends at 32 MB << 256 MB

  k_detect<<<1, 256, 0, stream>>>((const unsigned short*)q, flag);
  k_maskzero<<<2048, 256, 0, stream>>>(mask, flag);

  k_convert3<<<dim3(2048, 1, 3), 256, 0, stream>>>(q, k, v, qc, kc, vc, flag);
  k_convert<<<1, 256, 0, stream>>>(bo, boC, 1024, flag);

  k_transpose4<<<dim3(16, 16, 4), 256, 0, stream>>>(Wq, Wk, Wv, Wo, WqT, WkT,
                                                    WvT, WoT, flag);

  k_gemm3<<<dim3(8, 32, 3), 256, 0, stream>>>(qc, kc, vc, WqT, WkT, WvT, Qp, Kp,
                                              Vp, 0.125f);

  k_transpose_v<<<dim3(32, 16, 2), 256, 0, stream>>>(Vp, VTr);

  k_attn<<<dim3(32, 16, 2), 256, 0, stream>>>(Qp, Kp, VTr, mask, ob, AV, flag);

  const dim3 ggrid(8, 32);
  k_gemm_bt<<<ggrid, 256, 0, stream>>>(AV, WoT, nullptr, ob, boC, flag,
                                       4096, 1024, 1024, 1.0f);
}